// Round 17
// baseline (2026.225 us; speedup 1.0000x reference)
//
#include <hip/hip_runtime.h>

// ---------------------------------------------------------------------------
// RWKV-7 MoE FFN, MI355X (gfx950). bf16 MFMA + top-2 sparse expert dispatch.
// r17 = r16 with kshlora moved to gemm8p: a 256^2 8-phase counted-vmcnt
// pipeline (T3+T4+T5) with proven-disjoint staging schedule:
//   quadrant order (0,0),(0,1),(1,1),(1,0); per tile t:
//   p1 stages A-bot(t+1), p2 B-nq0(t+1), p3 A-top(t+2), p4 B-nq1(t+2);
//   one s_waitcnt vmcnt(4) per tile (never 0 in steady state); raw s_barrier.
// gemm_bt / gemm256 device code byte-identical to r14-r16 (72-VGPR roll);
// EPI_BF16 kept instantiated via address-take (rule #19).
// Shapes fixed: B=4 T=2048 C=2048 H=8192 R=64 E=4, topk=2.
// ---------------------------------------------------------------------------

#define DEV_INLINE __device__ __forceinline__

typedef __attribute__((ext_vector_type(8))) short bf16x8;
typedef __attribute__((ext_vector_type(4))) float f32x4;

DEV_INLINE unsigned short f2bf(float f) {
  union { float f; unsigned int u; } v; v.f = f;
  unsigned int u = v.u;
  unsigned int r = (u + 0x7FFFu + ((u >> 16) & 1u)) >> 16;  // RTNE
  return (unsigned short)r;
}
DEV_INLINE float bf2f(unsigned short s) {
  union { unsigned int u; float f; } v; v.u = ((unsigned int)s) << 16;
  return v.f;
}

// tbl ints: [0:8) hist[2][4], [8:16) fill[2][4], [16:26) base[2][5],
// [32:32+2*MB) blocktab[2][MB], [32+2*MB:...) tok[2][PR]

// ---------------------------------------------------------------------------
__global__ __launch_bounds__(256) void prep_kernel(
    const float* __restrict__ x, const float* __restrict__ x_prev,
    const float* __restrict__ x_k, unsigned short* __restrict__ h, int n0) {
  const int idx = blockIdx.x * 256 + threadIdx.x;
  const int c4 = idx & 511;
  const int gn = n0 + (idx >> 9);
  const int t  = gn & 2047;
  const int b  = gn >> 11;
  const float4 cur = ((const float4*)x)[(size_t)gn * 512 + c4];
  const float4 prv = (t == 0) ? ((const float4*)x_prev)[(b << 9) + c4]
                              : ((const float4*)x)[(size_t)gn * 512 - 512 + c4];
  const float4 k = ((const float4*)x_k)[c4];
  float hx = cur.x + (prv.x - cur.x) * k.x;
  float hy = cur.y + (prv.y - cur.y) * k.y;
  float hz = cur.z + (prv.z - cur.z) * k.z;
  float hw = cur.w + (prv.w - cur.w) * k.w;
  uint2 o;
  o.x = (unsigned int)f2bf(hx) | ((unsigned int)f2bf(hy) << 16);
  o.y = (unsigned int)f2bf(hz) | ((unsigned int)f2bf(hw) << 16);
  ((uint2*)h)[idx] = o;
}

__global__ __launch_bounds__(256) void xlast_kernel(
    const float* __restrict__ x, float* __restrict__ x_last) {
  const int i = blockIdx.x * 256 + threadIdx.x;
  const int b = i >> 9, c4 = i & 511;
  ((float4*)x_last)[i] =
      ((const float4*)x)[((size_t)b * 2048 + 2047) * 512 + c4];
}

__global__ __launch_bounds__(256) void transpose_cast(
    const float* __restrict__ in, unsigned short* __restrict__ outp,
    int rows, int cols) {
  __shared__ float tile[32][33];
  const int bx = blockIdx.x * 32, by = blockIdx.y * 32;
  const int tx = threadIdx.x, ty = threadIdx.y;
#pragma unroll
  for (int k = 0; k < 4; ++k)
    tile[ty + k * 8][tx] = in[(size_t)(by + ty + k * 8) * cols + bx + tx];
  __syncthreads();
#pragma unroll
  for (int k = 0; k < 4; ++k)
    outp[(size_t)(bx + ty + k * 8) * rows + by + tx] = f2bf(tile[tx][ty + k * 8]);
}

__global__ __launch_bounds__(256) void cast_bf16(
    const float* __restrict__ in, unsigned short* __restrict__ outp, int n4) {
  const int i = blockIdx.x * 256 + threadIdx.x;
  if (i >= n4) return;
  const float4 v = ((const float4*)in)[i];
  uint2 o;
  o.x = (unsigned int)f2bf(v.x) | ((unsigned int)f2bf(v.y) << 16);
  o.y = (unsigned int)f2bf(v.z) | ((unsigned int)f2bf(v.w) << 16);
  ((uint2*)outp)[i] = o;
}

__global__ void zero_page(unsigned int* zp) {
  if (threadIdx.x < 64) zp[threadIdx.x] = 0;
}

// ---------------------------------------------------------------------------
__global__ __launch_bounds__(256) void router_kernel(
    const float* __restrict__ x, const float* __restrict__ x_prev,
    const float* __restrict__ x_k, const float* __restrict__ Rt,
    int* __restrict__ tbl, int* __restrict__ etok,
    float* __restrict__ gate_tok, int MC, int n0) {
  const int lane = threadIdx.x & 63, wid = threadIdx.x >> 6;
  const int nl = blockIdx.x * 4 + wid;
  const int gn = n0 + nl;
  const int t = gn & 2047, b = gn >> 11;
  const float* cur = x + (size_t)gn * 2048;
  const float* prv = (t == 0) ? x_prev + (size_t)b * 2048 : cur - 2048;
  float hv[32];
#pragma unroll
  for (int j = 0; j < 32; ++j) {
    const int i = j * 64 + lane;
    const float xc = cur[i];
    hv[j] = xc + (prv[i] - xc) * x_k[i];
  }
  float s[4];
  s[0] = 0.f;
  for (int e = 1; e < 4; ++e) {
    const float* rrow = Rt + (size_t)(e - 1) * 2048;
    float a = 0.f;
#pragma unroll
    for (int j = 0; j < 32; ++j) a += hv[j] * rrow[j * 64 + lane];
#pragma unroll
    for (int d = 32; d >= 1; d >>= 1) a += __shfl_xor(a, d, 64);
    s[e] = a;
  }
  if (lane == 0) {
    int i1 = 0; float v1 = s[0];
    for (int e = 1; e < 4; ++e) if (s[e] > v1) { v1 = s[e]; i1 = e; }
    int i2 = -1; float v2 = -1e30f;
    for (int e = 0; e < 4; ++e) if (e != i1 && s[e] > v2) { v2 = s[e]; i2 = e; }
    const float ex = expf(v2 - v1);
    const float g1 = 1.f / (1.f + ex), g2 = ex / (1.f + ex);
    etok[nl] = i1;          etok[MC + nl] = i2;
    gate_tok[nl] = g1;      gate_tok[MC + nl] = g2;
    atomicAdd(&tbl[i1], 1); atomicAdd(&tbl[4 + i2], 1);
  }
}

__global__ void zero_hist(int* tbl) {
  if (threadIdx.x < 8) tbl[threadIdx.x] = 0;
}

__global__ __launch_bounds__(128) void seg_build(int* __restrict__ tbl, int MB) {
  const int tid = threadIdx.x;
  __shared__ int sbase[2][5];
  if (tid == 0) {
    for (int k = 0; k < 2; ++k) {
      int b = 0; sbase[k][0] = 0;
      for (int e = 0; e < 4; ++e) {
        b += ((tbl[k * 4 + e] + 127) >> 7) << 7;
        sbase[k][e + 1] = b;
      }
      for (int e = 0; e < 5; ++e) tbl[16 + k * 5 + e] = sbase[k][e];
    }
    for (int i = 0; i < 8; ++i) tbl[8 + i] = 0;
  }
  __syncthreads();
  int* bt = tbl + 32;
  for (int i = tid; i < 2 * MB; i += 128) {
    const int k = i / MB, row = (i % MB) * 128;
    int e = -1;
    for (int q = 0; q < 4; ++q)
      if (row >= sbase[k][q] && row < sbase[k][q + 1]) e = q;
    bt[i] = e;
  }
  int* tok = tbl + 32 + 2 * MB;
  for (int i = tid; i < 2 * MB * 128; i += 128) tok[i] = -1;
}

__global__ __launch_bounds__(256) void scatter_build(
    int* __restrict__ tbl, const int* __restrict__ etok, int MC, int MB) {
  const int t = blockIdx.x * 256 + threadIdx.x;
  if (t >= MC) return;
  int* tok = tbl + 32 + 2 * MB;
#pragma unroll
  for (int k = 0; k < 2; ++k) {
    const int e = etok[k * MC + t];
    const int r = atomicAdd(&tbl[8 + k * 4 + e], 1);
    tok[k * MB * 128 + tbl[16 + k * 5 + e] + r] = t;
  }
}

// ---------------------------------------------------------------------------
// gemm8p: 256x256 bf16 B^T GEMM, BK=64, 8 waves (2M x 4N), 8-phase pipeline.
// LDS: A/B each 2 bufs x [256 local rows][128B], halves of 128 rows.
// Staging granules (16KB, 2 loads/thread, pre-swizzled source, key=lrow&7):
//   A-top = local rows 0..63 of both M-halves; A-bot = rows 64..127;
//   B-nq0 = wave-col slices {0..31,64..95} of both N-halves; B-nq1 = +32.
// Per tile t: p1(q00) stage A-bot(t+1); p2(q01) stage B-nq0(t+1);
//             p3(q11) stage A-top(t+2); p4(q10) stage B-nq1(t+2);
// vmcnt(4) once per tile (0 at tail). Correctness: every granule read in
// tile t was issued <= t-1.p2, and vmcnt(4) at t-1 end allows only t-1.p3/p4
// (tile t+1 data) in flight => all tile-t reads landed. Dest regions are
// freed: A-top after p2 (read p1,p2 only), B-nq1 after p3 (read p2,p3),
// buf^1 regions belong to finished tile t-1.
// ---------------------------------------------------------------------------
__global__ __launch_bounds__(512, 1) void gemm8p(
    const unsigned short* __restrict__ A, int lda,
    const unsigned short* __restrict__ Bt, int ldb,
    unsigned short* __restrict__ C, int ldc, int K, int nbx) {
  __shared__ alignas(16) char As_[2][32768];
  __shared__ alignas(16) char Bs_[2][32768];
  const int nwg = gridDim.x, wg = blockIdx.x;
  const int q = nwg >> 3, r = nwg & 7;
  const int xcd = wg & 7, loc = wg >> 3;
  const int swz = (xcd < r ? xcd * (q + 1) : r * (q + 1) + (xcd - r) * q) + loc;
  const int bx = swz % nbx, by = swz / nbx;
  const int m0 = by * 256, n0 = bx * 256;
  const int tid = threadIdx.x, lane = tid & 63;
  const int wid = tid >> 6, wr = wid >> 2, wc = wid & 3;

  // ---- staging helpers (each: 16KB granule = 2 global_load_lds/thread) ----
  auto stageA = [&](int buf, int kt, int rbase) {  // rbase 0=top, 64=bot
#pragma unroll
    for (int j = 0; j < 2; ++j) {
      const int idx = j * 512 + tid;
      const int s = idx >> 3, w = idx & 7;   // s in [0,128)
      const int g = s >> 6, lrow = rbase + (s & 63);
      const unsigned short* src =
          A + (size_t)(m0 + g * 128 + lrow) * lda + kt + ((w ^ (lrow & 7)) * 8);
      __builtin_amdgcn_global_load_lds(
          (const __attribute__((address_space(1))) void*)src,
          (__attribute__((address_space(3))) void*)(
              &As_[buf][g * 16384 + lrow * 128 + w * 16]), 16, 0, 0);
    }
  };
  auto stageB = [&](int buf, int kt, int nq) {
#pragma unroll
    for (int j = 0; j < 2; ++j) {
      const int idx = j * 512 + tid;
      const int s = idx >> 3, w = idx & 7;
      const int g = s >> 5, half = g >> 1, grp = g & 1;
      const int lrow = grp * 64 + nq * 32 + (s & 31);
      const unsigned short* src =
          Bt + (size_t)(n0 + half * 128 + lrow) * ldb + kt +
          ((w ^ (lrow & 7)) * 8);
      __builtin_amdgcn_global_load_lds(
          (const __attribute__((address_space(1))) void*)src,
          (__attribute__((address_space(3))) void*)(
              &Bs_[buf][half * 16384 + lrow * 128 + w * 16]), 16, 0, 0);
    }
  };

  f32x4 acc[8][4] = {};
  bf16x8 afr[4][2], bfr[2][2];

#define READ_A(buf, mq)                                                      \
  _Pragma("unroll") for (int mf = 0; mf < 4; ++mf)                           \
  _Pragma("unroll") for (int ks = 0; ks < 2; ++ks) {                         \
    const int lr = (mq) * 64 + mf * 16 + (lane & 15);                        \
    afr[mf][ks] = *(const bf16x8*)(&As_[buf][wr * 16384 + lr * 128 +         \
        ((ks * 64 + ((lane >> 4) * 16)) ^ ((lr & 7) << 4))]);                \
  }
#define READ_B(buf, nq)                                                      \
  _Pragma("unroll") for (int nf = 0; nf < 2; ++nf)                           \
  _Pragma("unroll") for (int ks = 0; ks < 2; ++ks) {                         \
    const int gcl = wc * 64 + (nq) * 32 + nf * 16 + (lane & 15);             \
    const int hf = gcl >> 7, lr = gcl & 127;                                 \
    bfr[nf][ks] = *(const bf16x8*)(&Bs_[buf][hf * 16384 + lr * 128 +         \
        ((ks * 64 + ((lane >> 4) * 16)) ^ ((lr & 7) << 4))]);                \
  }
#define DO_MFMA(mq, nq)                                                      \
  __builtin_amdgcn_s_setprio(1);                                             \
  _Pragma("unroll") for (int ks = 0; ks < 2; ++ks)                           \
  _Pragma("unroll") for (int mf = 0; mf < 4; ++mf)                           \
  _Pragma("unroll") for (int nf = 0; nf < 2; ++nf)                           \
    acc[(mq) * 4 + mf][(nq) * 2 + nf] =                                      \
        __builtin_amdgcn_mfma_f32_16x16x32_bf16(                             \
            afr[mf][ks], bfr[nf][ks], acc[(mq) * 4 + mf][(nq) * 2 + nf],     \
            0, 0, 0);                                                        \
  __builtin_amdgcn_s_setprio(0);
#define GBAR asm volatile("s_barrier" ::: "memory")

  const int NT = K >> 6;
  // prologue: t0 full + t1 {A-top, B-nq1}; wait t0 (allow t1's 4 in flight)
  stageA(0, 0, 0); stageA(0, 0, 64); stageB(0, 0, 0); stageB(0, 0, 1);
  stageA(1, 64, 0); stageB(1, 64, 1);
  asm volatile("s_waitcnt vmcnt(4)" ::: "memory");
  GBAR;

  for (int t = 0; t < NT; ++t) {
    const int buf = t & 1, o = buf ^ 1;
    const int kt1 = (t + 1) << 6, kt2 = (t + 2) << 6;
    // p1 (0,0): stage A-bot(t+1)
    READ_A(buf, 0); READ_B(buf, 0);
    if (t + 1 < NT) stageA(o, kt1, 64);
    DO_MFMA(0, 0);
    GBAR;
    // p2 (0,1): stage B-nq0(t+1)
    READ_B(buf, 1);
    if (t + 1 < NT) stageB(o, kt1, 0);
    DO_MFMA(0, 1);
    GBAR;
    // p3 (1,1): stage A-top(t+2) into current buf (A-top freed after p2)
    READ_A(buf, 1);
    if (t + 2 < NT) stageA(buf, kt2, 0);
    DO_MFMA(1, 1);
    GBAR;
    // p4 (1,0): stage B-nq1(t+2) into current buf (B-nq1 freed after p3)
    READ_B(buf, 0);
    if (t + 2 < NT) stageB(buf, kt2, 1);
    DO_MFMA(1, 0);
    if (t + 2 < NT) { asm volatile("s_waitcnt vmcnt(4)" ::: "memory"); }
    else            { asm volatile("s_waitcnt vmcnt(0)" ::: "memory"); }
    GBAR;
  }
#undef READ_A
#undef READ_B
#undef DO_MFMA
#undef GBAR

  // epilogue: C/D layout col = lane&15, row = (lane>>4)*4 + j  [m89/m91]
  const int cc = lane & 15, cr0 = (lane >> 4) * 4;
#pragma unroll
  for (int mf = 0; mf < 8; ++mf)
#pragma unroll
    for (int nf = 0; nf < 4; ++nf)
#pragma unroll
      for (int j = 0; j < 4; ++j) {
        const int grow = m0 + wr * 128 + mf * 16 + cr0 + j;
        const int gcol = n0 + wc * 64 + nf * 16 + cc;
        C[(size_t)grow * ldc + gcol] = f2bf(acc[mf][nf][j]);
      }
}

// ---------------------------------------------------------------------------
// gemm256: dense bf16 B^T GEMM, 256x256 tile, BK=64, 8 waves, double-buffered
// LDS (128 KiB). Kept compiled (unlaunched) for codegen-set identity.
// ---------------------------------------------------------------------------
__global__ __launch_bounds__(512, 1) void gemm256(
    const unsigned short* __restrict__ A, int lda,
    const unsigned short* __restrict__ Bt, int ldb,
    unsigned short* __restrict__ C, int ldc, int K, int nbx) {
  __shared__ char smem[2][2][256 * 64 * 2];  // [buf][A/B][32 KB]
  const int nwg = gridDim.x, wg = blockIdx.x;
  const int q = nwg >> 3, r = nwg & 7;
  const int xcd = wg & 7, loc = wg >> 3;
  const int swz = (xcd < r ? xcd * (q + 1) : r * (q + 1) + (xcd - r) * q) + loc;
  const int bx = swz % nbx, by = swz / nbx;
  const int m0 = by * 256, n0 = bx * 256;
  const int tid = threadIdx.x, lane = tid & 63;
  const int wid = tid >> 6, wr = wid >> 2, wc = wid & 3;

  int arow[4], scol[4];
#pragma unroll
  for (int i = 0; i < 4; ++i) {
    const int qq = i * 512 + tid;
    const int row = qq >> 3, w = qq & 7;
    arow[i] = row;
    scol[i] = (w ^ (row & 7)) * 8;
  }

  f32x4 acc[8][4] = {};

  auto stage = [&](int buf, int kt) {
#pragma unroll
    for (int i = 0; i < 4; ++i) {
      const unsigned short* src =
          A + (size_t)(m0 + arow[i]) * lda + kt + scol[i];
      __builtin_amdgcn_global_load_lds(
          (const __attribute__((address_space(1))) void*)src,
          (__attribute__((address_space(3))) void*)(
              &smem[buf][0][(i * 512 + tid) * 16]), 16, 0, 0);
    }
#pragma unroll
    for (int i = 0; i < 4; ++i) {
      const unsigned short* src =
          Bt + (size_t)(n0 + arow[i]) * ldb + kt + scol[i];
      __builtin_amdgcn_global_load_lds(
          (const __attribute__((address_space(1))) void*)src,
          (__attribute__((address_space(3))) void*)(
              &smem[buf][1][(i * 512 + tid) * 16]), 16, 0, 0);
    }
  };

  stage(0, 0);
  asm volatile("s_waitcnt vmcnt(0)" ::: "memory");
  __syncthreads();

  const int NT = K >> 6;
  for (int t = 0; t < NT; ++t) {
    const int cur = t & 1;
    if (t + 1 < NT) stage(cur ^ 1, (t + 1) << 6);
    const char* As = smem[cur][0];
    const char* Bs = smem[cur][1];
#pragma unroll
    for (int ks = 0; ks < 2; ++ks) {
#pragma unroll
      for (int mh = 0; mh < 2; ++mh) {
        bf16x8 af[4];
#pragma unroll
        for (int m = 0; m < 4; ++m) {
          const int row = wr * 128 + mh * 64 + m * 16 + (lane & 15);
          const int kb = (ks * 64 + ((lane >> 4) * 16)) ^ ((row & 7) << 4);
          af[m] = *(const bf16x8*)(As + row * 128 + kb);
        }
#pragma unroll
        for (int nh = 0; nh < 2; ++nh) {
          bf16x8 bf[2];
#pragma unroll
          for (int n = 0; n < 2; ++n) {
            const int row = wc * 64 + nh * 32 + n * 16 + (lane & 15);
            const int kb = (ks * 64 + ((lane >> 4) * 16)) ^ ((row & 7) << 4);
            bf[n] = *(const bf16x8*)(Bs + row * 128 + kb);
          }
          __builtin_amdgcn_s_setprio(1);
#pragma unroll
          for (int m = 0; m < 4; ++m)
#pragma unroll
            for (int n = 0; n < 2; ++n)
              acc[mh * 4 + m][nh * 2 + n] =
                  __builtin_amdgcn_mfma_f32_16x16x32_bf16(
                      af[m], bf[n], acc[mh * 4 + m][nh * 2 + n], 0, 0, 0);
          __builtin_amdgcn_s_setprio(0);
        }
      }
    }
    asm volatile("s_waitcnt vmcnt(0)" ::: "memory");
    __syncthreads();
  }

  const int cc = lane & 15, cr0 = (lane >> 4) * 4;
#pragma unroll
  for (int mf = 0; mf < 8; ++mf)
#pragma unroll
    for (int nf = 0; nf < 4; ++nf)
#pragma unroll
      for (int j = 0; j < 4; ++j) {
        const int grow = m0 + wr * 128 + mf * 16 + cr0 + j;
        const int gcol = n0 + wc * 64 + nf * 16 + cc;
        C[(size_t)grow * ldc + gcol] = f2bf(acc[mf][nf][j]);
      }
}

// ---------------------------------------------------------------------------
// 128x128 B^T GEMM with expert segmentation / gather / scatter + slot merge.
// EPI_BF16: dense store bf16. EPI_KE: k_e = relu(aux[tok] + 2*acc)^2.
// EPI_GV: out/out2 pure write g*acc via tok scatter; bx==nbx-1 with B2: vat.
// EPI_VB0: out += 2g*acc. EPI_VB1: out += out2[t] + 2g*acc.
// ---------------------------------------------------------------------------
enum { EPI_BF16 = 0, EPI_KE = 1, EPI_GV = 2, EPI_VB0 = 3, EPI_VB1 = 4 };

template <int EPI>
__global__ __launch_bounds__(256) void gemm_bt(
    const unsigned short* __restrict__ A, int lda, long long strideAe,
    long long strideAslot,
    const unsigned short* __restrict__ B, int ldb, long long strideBe,
    const unsigned short* __restrict__ B2, const unsigned short* __restrict__ zp,
    void* __restrict__ Cp, int ldc, long long strideCslot,
    unsigned short* __restrict__ vatp, long long strideVat,
    const unsigned short* __restrict__ aux, int ldaux,
    const float* __restrict__ gate, const float* __restrict__ out2,
    float scale,
    const int* __restrict__ blocktab, const int* __restrict__ rowmap,
    const int* __restrict__ crowmap,
    int K, int nbx, int mbPerSlot, int PRr, int MCr) {
  constexpr int BM = 128, BN = 128, BK = 64;

  const int nwg = gridDim.x, wg = blockIdx.x;
  const int q = nwg >> 3, r = nwg & 7;
  const int xcd = wg & 7, loc = wg >> 3;
  const int swz = (xcd < r ? xcd * (q + 1) : r * (q + 1) + (xcd - r) * q) + loc;
  const int bx = swz % nbx;
  const int by = swz / nbx;

  int k = 0, byl = by;
  if (mbPerSlot > 0) { k = by / mbPerSlot; byl = by - k * mbPerSlot; }

  int e = 0;
  if (blocktab) { e = blocktab[by]; if (e < 0) return; }

  __shared__ alignas(16) char smem[(BM + BN) * BK * 2];
  char* As = smem;
  char* Bs = smem + BM * BK * 2;

  const unsigned short* Ae = A + (size_t)e * strideAe + (size_t)k * strideAslot;
  const bool vatBlk = (EPI == EPI_GV) && (B2 != nullptr) && (bx == nbx - 1);

  const int tid = threadIdx.x;
  const int lane = tid & 63;
  const int wid = tid >> 6;
  const int wr = wid >> 1, wc = wid & 1;
  const int m0 = byl * BM;
  const int bn0 = bx * BN;

  const int* tokA = rowmap ? rowmap + k * PRr : nullptr;
  int arow[4];
#pragma unroll
  for (int i = 0; i < 4; ++i) {
    const int row = (i * 256 + tid) >> 3;
    int rr = m0 + row;
    if (tokA) { rr = tokA[rr]; if (rr < 0) rr = 0; }
    arow[i] = rr;
  }

  f32x4 acc[4][4] = {};

  for (int kt = 0; kt < K; kt += BK) {
    __syncthreads();
#pragma unroll
    for (int i = 0; i < 4; ++i) {
      const int qq = i * 256 + tid;
      const int row = qq >> 3, w = qq & 7;
      const int g = w ^ (row & 7);
      const unsigned short* src = Ae + (size_t)arow[i] * lda + kt + g * 8;
      __builtin_amdgcn_global_load_lds(
          (const __attribute__((address_space(1))) void*)src,
          (__attribute__((address_space(3))) void*)(As + qq * 16), 16, 0, 0);
    }
#pragma unroll
    for (int i = 0; i < 4; ++i) {
      const int qq = i * 256 + tid;
      const int row = qq >> 3, w = qq & 7;
      const int g = w ^ (row & 7);
      const unsigned short* src;
      if (vatBlk) {
        src = (row < 64) ? B2 + ((size_t)e * 64 + row) * ldb + kt + g * 8
                         : (const unsigned short*)zp;
      } else {
        src = B + (size_t)e * strideBe + (size_t)(bn0 + row) * ldb + kt + g * 8;
      }
      __builtin_amdgcn_global_load_lds(
          (const __attribute__((address_space(1))) void*)src,
          (__attribute__((address_space(3))) void*)(Bs + qq * 16), 16, 0, 0);
    }
    asm volatile("s_waitcnt vmcnt(0)" ::: "memory");
    __syncthreads();

#pragma unroll
    for (int ks = 0; ks < 2; ++ks) {
      bf16x8 af[4], bfr[4];
#pragma unroll
      for (int m = 0; m < 4; ++m) {
        const int row = wr * 64 + m * 16 + (lane & 15);
        const int kb = (ks * 64 + ((lane >> 4) * 16)) ^ ((row & 7) << 4);
        af[m] = *(const bf16x8*)(As + row * 128 + kb);
      }
#pragma unroll
      for (int n = 0; n < 4; ++n) {
        const int row = wc * 64 + n * 16 + (lane & 15);
        const int kb = (ks * 64 + ((lane >> 4) * 16)) ^ ((row & 7) << 4);
        bfr[n] = *(const bf16x8*)(Bs + row * 128 + kb);
      }
#pragma unroll
      for (int m = 0; m < 4; ++m)
#pragma unroll
        for (int n = 0; n < 4; ++n)
          acc[m][n] = __builtin_amdgcn_mfma_f32_16x16x32_bf16(
              af[m], bfr[n], acc[m][n], 0, 0, 0);
    }
  }

  // epilogue: C/D layout col = lane&15, row = (lane>>4)*4 + j  [m89/m91]
  const int cc = lane & 15;
  const int cr0 = (lane >> 4) * 4;
#pragma unroll
  for (int m = 0; m < 4; ++m) {
#pragma unroll
    for (int n = 0; n < 4; ++n) {
#pragma unroll
      for (int j = 0; j < 4; ++j) {
        const int grow = m0 + wr * 64 + m * 16 + cr0 + j;
        const int lcol = wc * 64 + n * 16 + cc;
        const float v = acc[m][n][j];
        if constexpr (EPI == EPI_BF16) {
          ((unsigned short*)Cp)[(size_t)grow * ldc + bn0 + lcol] = f2bf(v);
        } else if constexpr (EPI == EPI_KE) {
          int ar = grow;
          if (tokA) { ar = tokA[grow]; if (ar < 0) ar = 0; }
          const float ksv = bf2f(aux[(size_t)ar * ldaux + bn0 + lcol]);
          float rr = ksv + 2.0f * v;  // LORA_SCALING = 2
          rr = rr > 0.f ? rr : 0.f;
          ((unsigned short*)Cp + (size_t)k * strideCslot)
              [(size_t)grow * ldc + bn0 + lcol] = f2bf(rr * rr);
        } else if constexpr (EPI == EPI_GV) {
          if (vatBlk) {
            if (lcol < 64)
              (vatp + (size_t)k * strideVat)[(size_t)grow * 64 + lcol] = f2bf(v);
          } else {
            const int t = crowmap[k * PRr + grow];
            if (t >= 0) {
              const float g = gate[k * MCr + t] * scale;
              ((float*)Cp + (size_t)k * strideCslot)[(size_t)t * ldc + bn0 + lcol] =
                  g * v;
            }
          }
        } else if constexpr (EPI == EPI_VB0) {
          const int t = crowmap[grow];
          if (t >= 0) {
            const float g = gate[t] * scale;
            float* o = (float*)Cp + (size_t)t * ldc + bn0 + lcol;
            *o = *o + g * v;
          }
        } else {  // EPI_VB1
          const int t = crowmap[grow];
          if (t >= 0) {
            const float g = gate[t] * scale;
            float* o = (float*)Cp + (size_t)t * ldc + bn0 + lcol;
            *o = *o + out2[(size_t)t * ldc + bn0 + lcol] + g * v;
          }
        }
      }
    }
  }
}

// ---------------------------------------------------------------------------
extern "C" void kernel_launch(void* const* d_in, const int* in_sizes, int n_in,
                              void* d_out, int out_size, void* d_ws,
                              size_t ws_size, hipStream_t stream) {
  (void)in_sizes; (void)n_in; (void)out_size;
  const float* x      = (const float*)d_in[0];
  const float* x_prev = (const float*)d_in[1];
  const float* x_k    = (const float*)d_in[2];
  const float* Router = (const float*)d_in[3];
  const float* K_ref  = (const float*)d_in[4];
  const float* V_ref  = (const float*)d_in[5];
  const float* Ka     = (const float*)d_in[6];
  const float* Kb     = (const float*)d_in[7];
  const float* Va     = (const float*)d_in[8];
  const float* Vb     = (const float*)d_in[9];

  // keep r14-r16 template-instantiation set (rule #19): EPI_BF16 unlaunched
  static auto keep_bf16 = &gemm_bt<EPI_BF16>;
  (void)keep_bf16;

  constexpr int Bb = 4, T = 2048, C = 2048, H = 8192, R = 64, E = 4;
  constexpr int M = Bb * T;       // 8192 tokens
  constexpr int NKL = H + E * R;  // 8448: [ksh | lora] cols = KtKa rows

  const size_t PAD = 255;
  auto rnd = [&](size_t b) { return (b + PAD) & ~PAD; };
  const size_t persist = rnd((size_t)NKL * C * 2)     // KtKa
                       + rnd((size_t)C * H * 2)       // Vt
                       + rnd((size_t)E * H * R * 2)   // KbB
                       + rnd((size_t)E * R * H * 2)   // VaB
                       + rnd((size_t)E * C * R * 2)   // VbB
                       + rnd(256);                    // zero page

  // largest MC (pow2 mult of 256): single k_e (aliases h_c), ksl [MC][NKL]
  // (aliases out2 f32), sequential slots.
  int MC = 0;
  for (int cand = M; cand >= 1024; cand >>= 1) {
    const int mb = cand / 128 + 4;
    const long long pr = (long long)mb * 128;
    size_t keSpan = rnd((size_t)pr * H * 2);            // k_e  >= h_c
    if (keSpan < rnd((size_t)cand * C * 2)) keSpan = rnd((size_t)cand * C * 2);
    size_t kslSpan = rnd((size_t)cand * NKL * 2);       // ksl >= out2 f32
    if (kslSpan < rnd((size_t)cand * C * 4)) kslSpan = rnd((size_t)cand * C * 4);
    const size_t need = persist + keSpan + kslSpan
                      + rnd((size_t)2 * pr * 64 * 2)    // vat[2]
                      + rnd((size_t)(32 + 2 * mb + 2 * pr) * 4)
                      + rnd((size_t)2 * cand * 4)       // etok
                      + rnd((size_t)2 * cand * 4);      // gtok
    if (need <= ws_size) { MC = cand; break; }
  }
  if (MC == 0) return;
  const int MB = MC / 128 + 4;
  const int PR = MB * 128;

  char* ws = (char*)d_ws;
  size_t off = 0;
  auto alloc = [&](size_t bytes) -> char* {
    char* p = ws + off; off += rnd(bytes); return p;
  };
  unsigned short* KtKa = (unsigned short*)alloc((size_t)NKL * C * 2);
  unsigned short* Vt   = (unsigned short*)alloc((size_t)C * H * 2);
  unsigned short* KbB  = (unsigned short*)alloc((size_t)E * H * R * 2);
  unsigned short* VaB  = (unsigned short*)alloc((size_t)E * R * H * 2);
  unsigned short* VbB  = (unsigned short*)alloc((size_t)E * C * R * 2);
  unsigned short* zp   = (unsigned short*)alloc(256);
  size_t keBytes = rnd((size_t)PR * H * 2);
  if (keBytes < rnd((size_t)MC * C * 2)) keBytes = rnd((size_t)MC * C * 2);
  unsigned short* k_e  = (unsigned short*)alloc(keBytes);
  size_t kslBytes = rnd((size_t)MC * NKL * 2);
  if (kslBytes < rnd((size_t)MC * C * 4)) kslBytes = rnd((size_t)MC * C * 4);
  unsigned short* ksl  = (unsigned short*)alloc(kslBytes);
  unsigned short* vat  = (unsigned short*)alloc((size_t)2 * PR * 64 * 2);
  int*            tbl  = (int*)alloc((size_t)(32 + 2 * MB + 2 * PR) * 4);
  int*            etok = (int*)alloc((size_t)2 * MC * 4);
  float*          gtok = (float*)alloc((size_t)2 * MC * 4);
  unsigned short* h_c  = k_e;          // alias: h dead after kshlora GEMM
  float*          out2 = (float*)ksl;  // alias: ksl dead after KE slot1

  float* out    = (float*)d_out;
  float* x_last = out + (size_t)M * C;

  // ---- one-time: weights -> bf16 (KtKa = [K_ref^T ; KaAll]) ----
  transpose_cast<<<dim3(H / 32, C / 32), dim3(32, 8), 0, stream>>>(K_ref, KtKa, C, H);
  cast_bf16<<<(E * R * C / 4 + 255) / 256, 256, 0, stream>>>(
      Ka, KtKa + (size_t)H * C, E * R * C / 4);
  transpose_cast<<<dim3(C / 32, H / 32), dim3(32, 8), 0, stream>>>(V_ref, Vt, H, C);
  cast_bf16<<<(E * H * R / 4 + 255) / 256, 256, 0, stream>>>(Kb, KbB, E * H * R / 4);
  cast_bf16<<<(E * R * H / 4 + 255) / 256, 256, 0, stream>>>(Va, VaB, E * R * H / 4);
  cast_bf16<<<(E * C * R / 4 + 255) / 256, 256, 0, stream>>>(Vb, VbB, E * C * R / 4);
  zero_page<<<1, 64, 0, stream>>>((unsigned int*)zp);
  xlast_kernel<<<Bb * C / 4 / 256, 256, 0, stream>>>(x, x_last);

  // ---- per-chunk pipeline (sequential slots, single k_e) ----
  for (int c0 = 0; c0 < M; c0 += MC) {
    float* outc = out + (size_t)c0 * C;
    prep_kernel<<<MC * C / 4 / 256, 256, 0, stream>>>(x, x_prev, x_k, h_c, c0);
    zero_hist<<<1, 64, 0, stream>>>(tbl);
    router_kernel<<<MC / 4, 256, 0, stream>>>(x, x_prev, x_k, Router, tbl,
                                              etok, gtok, MC, c0);
    seg_build<<<1, 128, 0, stream>>>(tbl, MB);
    scatter_build<<<(MC + 255) / 256, 256, 0, stream>>>(tbl, etok, MC, MB);

    const int* bt  = tbl + 32;
    const int* tok = tbl + 32 + 2 * MB;

    // [ksh | lora] = h @ [K_ref^T ; KaAll]  [MC x 8448], K=C — 8-phase 256^2
    gemm8p<<<(MC / 256) * (NKL / 256), 512, 0, stream>>>(
        h_c, C, KtKa, C, ksl, NKL, C, NKL / 256);

    for (int k = 0; k < 2; ++k) {
      const int* btk  = bt + k * MB;
      const int* tokk = tok + k * PR;
      const float* gk = gtok + (size_t)k * MC;

      // k_e = relu(ksh[tok] + 2*lora[tok,e] @ Kb[e]^T)^2  [PR x H], K=R
      gemm_bt<EPI_KE><<<(H / 128) * MB, 256, 0, stream>>>(
          ksl + H, NKL, 64, 0, KbB, R, (long long)H * R, nullptr, nullptr,
          k_e, H, 0, nullptr, 0, ksl, NKL, nullptr, nullptr, 0.f,
          btk, tokk, nullptr, R, H / 128, 0, PR, MC);

      // pure-write GV: slot0 -> out f32, slot1 -> out2 f32; vat via VaB/zp
      gemm_bt<EPI_GV><<<(C / 128 + 1) * MB, 256, 0, stream>>>(
          k_e, H, 0, 0, Vt, H, 0, VaB, zp,
          (k == 0) ? (void*)outc : (void*)out2, C, 0,
          vat + (size_t)k * PR * 64, 0, nullptr, 0, gk, nullptr, 1.0f,
          btk, nullptr, tokk, H, C / 128 + 1, 0, PR, MC);

      // out += [k==1: out2] + 2*g*(vat_k @ Vb[e]^T)   [PR x C], K=R
      if (k == 0) {
        gemm_bt<EPI_VB0><<<(C / 128) * MB, 256, 0, stream>>>(
            vat, 64, 0, 0, VbB, R, (long long)C * R, nullptr, nullptr,
            outc, C, 0, nullptr, 0, nullptr, 0, gk, nullptr, 2.0f,
            btk, nullptr, tokk, R, C / 128, 0, PR, MC);
      } else {
        gemm_bt<EPI_VB1><<<(C / 128) * MB, 256, 0, stream>>>(
            vat + (size_t)PR * 64, 64, 0, 0, VbB, R, (long long)C * R,
            nullptr, nullptr, outc, C, 0, nullptr, 0, nullptr, 0,
            gk, out2, 2.0f,
            btk, nullptr, tokk, R, C / 128, 0, PR, MC);
      }
    }
  }
}

// Round 18
// 2017.409 us; speedup vs baseline: 1.0044x; 1.0044x over previous
//
#include <hip/hip_runtime.h>

// ---------------------------------------------------------------------------
// RWKV-7 MoE FFN, MI355X (gfx950). bf16 MFMA + top-2 sparse expert dispatch.
// FINAL (r18 = r16 byte-for-byte, the best-measured configuration, 2025.7us):
//  - top-2 compacted slot-lists (expert-sorted, 128-padded segments)
//  - kshlora merge: [ksh|lora] = h @ [K_ref^T ; KaAll] in one 128^2 GEMM
//  - sequential slots, single k_e buffer; h_c aliases k_e; out2 aliases ksl
//  - pure-write GV epilogues (slot0 -> out f32 init, slot1 -> out2 f32),
//    vat fused as an extra n-block (VaB rows + zero page)
//  - VB1 folds out2 back while applying the vat@Vb^T correction
//  - XCD-bijective block swizzle on all GEMMs; global_load_lds w16 staging
//    with XOR-swizzled LDS (pre-swizzled global source)
// Device code frozen at the 72-VGPR codegen roll (rule #19): gemm256 kept
// compiled-unlaunched; all 5 gemm_bt EPIs instantiated.
// Shapes fixed: B=4 T=2048 C=2048 H=8192 R=64 E=4, topk=2.
// ---------------------------------------------------------------------------

#define DEV_INLINE __device__ __forceinline__

typedef __attribute__((ext_vector_type(8))) short bf16x8;
typedef __attribute__((ext_vector_type(4))) float f32x4;

DEV_INLINE unsigned short f2bf(float f) {
  union { float f; unsigned int u; } v; v.f = f;
  unsigned int u = v.u;
  unsigned int r = (u + 0x7FFFu + ((u >> 16) & 1u)) >> 16;  // RTNE
  return (unsigned short)r;
}
DEV_INLINE float bf2f(unsigned short s) {
  union { unsigned int u; float f; } v; v.u = ((unsigned int)s) << 16;
  return v.f;
}

// tbl ints: [0:8) hist[2][4], [8:16) fill[2][4], [16:26) base[2][5],
// [32:32+2*MB) blocktab[2][MB], [32+2*MB:...) tok[2][PR]

// ---------------------------------------------------------------------------
__global__ __launch_bounds__(256) void prep_kernel(
    const float* __restrict__ x, const float* __restrict__ x_prev,
    const float* __restrict__ x_k, unsigned short* __restrict__ h, int n0) {
  const int idx = blockIdx.x * 256 + threadIdx.x;
  const int c4 = idx & 511;
  const int gn = n0 + (idx >> 9);
  const int t  = gn & 2047;
  const int b  = gn >> 11;
  const float4 cur = ((const float4*)x)[(size_t)gn * 512 + c4];
  const float4 prv = (t == 0) ? ((const float4*)x_prev)[(b << 9) + c4]
                              : ((const float4*)x)[(size_t)gn * 512 - 512 + c4];
  const float4 k = ((const float4*)x_k)[c4];
  float hx = cur.x + (prv.x - cur.x) * k.x;
  float hy = cur.y + (prv.y - cur.y) * k.y;
  float hz = cur.z + (prv.z - cur.z) * k.z;
  float hw = cur.w + (prv.w - cur.w) * k.w;
  uint2 o;
  o.x = (unsigned int)f2bf(hx) | ((unsigned int)f2bf(hy) << 16);
  o.y = (unsigned int)f2bf(hz) | ((unsigned int)f2bf(hw) << 16);
  ((uint2*)h)[idx] = o;
}

__global__ __launch_bounds__(256) void xlast_kernel(
    const float* __restrict__ x, float* __restrict__ x_last) {
  const int i = blockIdx.x * 256 + threadIdx.x;
  const int b = i >> 9, c4 = i & 511;
  ((float4*)x_last)[i] =
      ((const float4*)x)[((size_t)b * 2048 + 2047) * 512 + c4];
}

__global__ __launch_bounds__(256) void transpose_cast(
    const float* __restrict__ in, unsigned short* __restrict__ outp,
    int rows, int cols) {
  __shared__ float tile[32][33];
  const int bx = blockIdx.x * 32, by = blockIdx.y * 32;
  const int tx = threadIdx.x, ty = threadIdx.y;
#pragma unroll
  for (int k = 0; k < 4; ++k)
    tile[ty + k * 8][tx] = in[(size_t)(by + ty + k * 8) * cols + bx + tx];
  __syncthreads();
#pragma unroll
  for (int k = 0; k < 4; ++k)
    outp[(size_t)(bx + ty + k * 8) * rows + by + tx] = f2bf(tile[tx][ty + k * 8]);
}

__global__ __launch_bounds__(256) void cast_bf16(
    const float* __restrict__ in, unsigned short* __restrict__ outp, int n4) {
  const int i = blockIdx.x * 256 + threadIdx.x;
  if (i >= n4) return;
  const float4 v = ((const float4*)in)[i];
  uint2 o;
  o.x = (unsigned int)f2bf(v.x) | ((unsigned int)f2bf(v.y) << 16);
  o.y = (unsigned int)f2bf(v.z) | ((unsigned int)f2bf(v.w) << 16);
  ((uint2*)outp)[i] = o;
}

__global__ void zero_page(unsigned int* zp) {
  if (threadIdx.x < 64) zp[threadIdx.x] = 0;
}

// ---------------------------------------------------------------------------
__global__ __launch_bounds__(256) void router_kernel(
    const float* __restrict__ x, const float* __restrict__ x_prev,
    const float* __restrict__ x_k, const float* __restrict__ Rt,
    int* __restrict__ tbl, int* __restrict__ etok,
    float* __restrict__ gate_tok, int MC, int n0) {
  const int lane = threadIdx.x & 63, wid = threadIdx.x >> 6;
  const int nl = blockIdx.x * 4 + wid;
  const int gn = n0 + nl;
  const int t = gn & 2047, b = gn >> 11;
  const float* cur = x + (size_t)gn * 2048;
  const float* prv = (t == 0) ? x_prev + (size_t)b * 2048 : cur - 2048;
  float hv[32];
#pragma unroll
  for (int j = 0; j < 32; ++j) {
    const int i = j * 64 + lane;
    const float xc = cur[i];
    hv[j] = xc + (prv[i] - xc) * x_k[i];
  }
  float s[4];
  s[0] = 0.f;
  for (int e = 1; e < 4; ++e) {
    const float* rrow = Rt + (size_t)(e - 1) * 2048;
    float a = 0.f;
#pragma unroll
    for (int j = 0; j < 32; ++j) a += hv[j] * rrow[j * 64 + lane];
#pragma unroll
    for (int d = 32; d >= 1; d >>= 1) a += __shfl_xor(a, d, 64);
    s[e] = a;
  }
  if (lane == 0) {
    int i1 = 0; float v1 = s[0];
    for (int e = 1; e < 4; ++e) if (s[e] > v1) { v1 = s[e]; i1 = e; }
    int i2 = -1; float v2 = -1e30f;
    for (int e = 0; e < 4; ++e) if (e != i1 && s[e] > v2) { v2 = s[e]; i2 = e; }
    const float ex = expf(v2 - v1);
    const float g1 = 1.f / (1.f + ex), g2 = ex / (1.f + ex);
    etok[nl] = i1;          etok[MC + nl] = i2;
    gate_tok[nl] = g1;      gate_tok[MC + nl] = g2;
    atomicAdd(&tbl[i1], 1); atomicAdd(&tbl[4 + i2], 1);
  }
}

__global__ void zero_hist(int* tbl) {
  if (threadIdx.x < 8) tbl[threadIdx.x] = 0;
}

__global__ __launch_bounds__(128) void seg_build(int* __restrict__ tbl, int MB) {
  const int tid = threadIdx.x;
  __shared__ int sbase[2][5];
  if (tid == 0) {
    for (int k = 0; k < 2; ++k) {
      int b = 0; sbase[k][0] = 0;
      for (int e = 0; e < 4; ++e) {
        b += ((tbl[k * 4 + e] + 127) >> 7) << 7;
        sbase[k][e + 1] = b;
      }
      for (int e = 0; e < 5; ++e) tbl[16 + k * 5 + e] = sbase[k][e];
    }
    for (int i = 0; i < 8; ++i) tbl[8 + i] = 0;
  }
  __syncthreads();
  int* bt = tbl + 32;
  for (int i = tid; i < 2 * MB; i += 128) {
    const int k = i / MB, row = (i % MB) * 128;
    int e = -1;
    for (int q = 0; q < 4; ++q)
      if (row >= sbase[k][q] && row < sbase[k][q + 1]) e = q;
    bt[i] = e;
  }
  int* tok = tbl + 32 + 2 * MB;
  for (int i = tid; i < 2 * MB * 128; i += 128) tok[i] = -1;
}

__global__ __launch_bounds__(256) void scatter_build(
    int* __restrict__ tbl, const int* __restrict__ etok, int MC, int MB) {
  const int t = blockIdx.x * 256 + threadIdx.x;
  if (t >= MC) return;
  int* tok = tbl + 32 + 2 * MB;
#pragma unroll
  for (int k = 0; k < 2; ++k) {
    const int e = etok[k * MC + t];
    const int r = atomicAdd(&tbl[8 + k * 4 + e], 1);
    tok[k * MB * 128 + tbl[16 + k * 5 + e] + r] = t;
  }
}

// ---------------------------------------------------------------------------
// gemm256: dense bf16 B^T GEMM, 256x256 tile, BK=64, 8 waves, double-buffered
// LDS (128 KiB). Kept compiled (unlaunched) for codegen-set identity.
// ---------------------------------------------------------------------------
__global__ __launch_bounds__(512, 1) void gemm256(
    const unsigned short* __restrict__ A, int lda,
    const unsigned short* __restrict__ Bt, int ldb,
    unsigned short* __restrict__ C, int ldc, int K, int nbx) {
  __shared__ char smem[2][2][256 * 64 * 2];  // [buf][A/B][32 KB]
  const int nwg = gridDim.x, wg = blockIdx.x;
  const int q = nwg >> 3, r = nwg & 7;
  const int xcd = wg & 7, loc = wg >> 3;
  const int swz = (xcd < r ? xcd * (q + 1) : r * (q + 1) + (xcd - r) * q) + loc;
  const int bx = swz % nbx, by = swz / nbx;
  const int m0 = by * 256, n0 = bx * 256;
  const int tid = threadIdx.x, lane = tid & 63;
  const int wid = tid >> 6, wr = wid >> 2, wc = wid & 3;

  int arow[4], scol[4];
#pragma unroll
  for (int i = 0; i < 4; ++i) {
    const int qq = i * 512 + tid;
    const int row = qq >> 3, w = qq & 7;
    arow[i] = row;
    scol[i] = (w ^ (row & 7)) * 8;
  }

  f32x4 acc[8][4] = {};

  auto stage = [&](int buf, int kt) {
#pragma unroll
    for (int i = 0; i < 4; ++i) {
      const unsigned short* src =
          A + (size_t)(m0 + arow[i]) * lda + kt + scol[i];
      __builtin_amdgcn_global_load_lds(
          (const __attribute__((address_space(1))) void*)src,
          (__attribute__((address_space(3))) void*)(
              &smem[buf][0][(i * 512 + tid) * 16]), 16, 0, 0);
    }
#pragma unroll
    for (int i = 0; i < 4; ++i) {
      const unsigned short* src =
          Bt + (size_t)(n0 + arow[i]) * ldb + kt + scol[i];
      __builtin_amdgcn_global_load_lds(
          (const __attribute__((address_space(1))) void*)src,
          (__attribute__((address_space(3))) void*)(
              &smem[buf][1][(i * 512 + tid) * 16]), 16, 0, 0);
    }
  };

  stage(0, 0);
  asm volatile("s_waitcnt vmcnt(0)" ::: "memory");
  __syncthreads();

  const int NT = K >> 6;
  for (int t = 0; t < NT; ++t) {
    const int cur = t & 1;
    if (t + 1 < NT) stage(cur ^ 1, (t + 1) << 6);
    const char* As = smem[cur][0];
    const char* Bs = smem[cur][1];
#pragma unroll
    for (int ks = 0; ks < 2; ++ks) {
#pragma unroll
      for (int mh = 0; mh < 2; ++mh) {
        bf16x8 af[4];
#pragma unroll
        for (int m = 0; m < 4; ++m) {
          const int row = wr * 128 + mh * 64 + m * 16 + (lane & 15);
          const int kb = (ks * 64 + ((lane >> 4) * 16)) ^ ((row & 7) << 4);
          af[m] = *(const bf16x8*)(As + row * 128 + kb);
        }
#pragma unroll
        for (int nh = 0; nh < 2; ++nh) {
          bf16x8 bf[2];
#pragma unroll
          for (int n = 0; n < 2; ++n) {
            const int row = wc * 64 + nh * 32 + n * 16 + (lane & 15);
            const int kb = (ks * 64 + ((lane >> 4) * 16)) ^ ((row & 7) << 4);
            bf[n] = *(const bf16x8*)(Bs + row * 128 + kb);
          }
          __builtin_amdgcn_s_setprio(1);
#pragma unroll
          for (int m = 0; m < 4; ++m)
#pragma unroll
            for (int n = 0; n < 2; ++n)
              acc[mh * 4 + m][nh * 2 + n] =
                  __builtin_amdgcn_mfma_f32_16x16x32_bf16(
                      af[m], bf[n], acc[mh * 4 + m][nh * 2 + n], 0, 0, 0);
          __builtin_amdgcn_s_setprio(0);
        }
      }
    }
    asm volatile("s_waitcnt vmcnt(0)" ::: "memory");
    __syncthreads();
  }

  const int cc = lane & 15, cr0 = (lane >> 4) * 4;
#pragma unroll
  for (int mf = 0; mf < 8; ++mf)
#pragma unroll
    for (int nf = 0; nf < 4; ++nf)
#pragma unroll
      for (int j = 0; j < 4; ++j) {
        const int grow = m0 + wr * 128 + mf * 16 + cr0 + j;
        const int gcol = n0 + wc * 64 + nf * 16 + cc;
        C[(size_t)grow * ldc + gcol] = f2bf(acc[mf][nf][j]);
      }
}

// ---------------------------------------------------------------------------
// 128x128 B^T GEMM with expert segmentation / gather / scatter + slot merge.
// EPI_BF16: dense store bf16 (kshlora).
// EPI_KE:   k_e = relu(aux[tok] + 2*acc)^2.
// EPI_GV:   out/out2 pure write g*acc via tok scatter; bx==nbx-1 with B2:
//           vat tile (B = VaB rows 0..63, zero page rows 64..127).
// EPI_VB0:  out += 2g*acc (per-slot launch).
// EPI_VB1:  out += out2[t] + 2g*acc (per-slot launch, folds the slot1 merge).
// ---------------------------------------------------------------------------
enum { EPI_BF16 = 0, EPI_KE = 1, EPI_GV = 2, EPI_VB0 = 3, EPI_VB1 = 4 };

template <int EPI>
__global__ __launch_bounds__(256) void gemm_bt(
    const unsigned short* __restrict__ A, int lda, long long strideAe,
    long long strideAslot,
    const unsigned short* __restrict__ B, int ldb, long long strideBe,
    const unsigned short* __restrict__ B2, const unsigned short* __restrict__ zp,
    void* __restrict__ Cp, int ldc, long long strideCslot,
    unsigned short* __restrict__ vatp, long long strideVat,
    const unsigned short* __restrict__ aux, int ldaux,
    const float* __restrict__ gate, const float* __restrict__ out2,
    float scale,
    const int* __restrict__ blocktab, const int* __restrict__ rowmap,
    const int* __restrict__ crowmap,
    int K, int nbx, int mbPerSlot, int PRr, int MCr) {
  constexpr int BM = 128, BN = 128, BK = 64;

  const int nwg = gridDim.x, wg = blockIdx.x;
  const int q = nwg >> 3, r = nwg & 7;
  const int xcd = wg & 7, loc = wg >> 3;
  const int swz = (xcd < r ? xcd * (q + 1) : r * (q + 1) + (xcd - r) * q) + loc;
  const int bx = swz % nbx;
  const int by = swz / nbx;

  int k = 0, byl = by;
  if (mbPerSlot > 0) { k = by / mbPerSlot; byl = by - k * mbPerSlot; }

  int e = 0;
  if (blocktab) { e = blocktab[by]; if (e < 0) return; }

  __shared__ alignas(16) char smem[(BM + BN) * BK * 2];
  char* As = smem;
  char* Bs = smem + BM * BK * 2;

  const unsigned short* Ae = A + (size_t)e * strideAe + (size_t)k * strideAslot;
  const bool vatBlk = (EPI == EPI_GV) && (B2 != nullptr) && (bx == nbx - 1);

  const int tid = threadIdx.x;
  const int lane = tid & 63;
  const int wid = tid >> 6;
  const int wr = wid >> 1, wc = wid & 1;
  const int m0 = byl * BM;
  const int bn0 = bx * BN;

  const int* tokA = rowmap ? rowmap + k * PRr : nullptr;
  int arow[4];
#pragma unroll
  for (int i = 0; i < 4; ++i) {
    const int row = (i * 256 + tid) >> 3;
    int rr = m0 + row;
    if (tokA) { rr = tokA[rr]; if (rr < 0) rr = 0; }
    arow[i] = rr;
  }

  f32x4 acc[4][4] = {};

  for (int kt = 0; kt < K; kt += BK) {
    __syncthreads();
#pragma unroll
    for (int i = 0; i < 4; ++i) {
      const int qq = i * 256 + tid;
      const int row = qq >> 3, w = qq & 7;
      const int g = w ^ (row & 7);
      const unsigned short* src = Ae + (size_t)arow[i] * lda + kt + g * 8;
      __builtin_amdgcn_global_load_lds(
          (const __attribute__((address_space(1))) void*)src,
          (__attribute__((address_space(3))) void*)(As + qq * 16), 16, 0, 0);
    }
#pragma unroll
    for (int i = 0; i < 4; ++i) {
      const int qq = i * 256 + tid;
      const int row = qq >> 3, w = qq & 7;
      const int g = w ^ (row & 7);
      const unsigned short* src;
      if (vatBlk) {
        src = (row < 64) ? B2 + ((size_t)e * 64 + row) * ldb + kt + g * 8
                         : (const unsigned short*)zp;
      } else {
        src = B + (size_t)e * strideBe + (size_t)(bn0 + row) * ldb + kt + g * 8;
      }
      __builtin_amdgcn_global_load_lds(
          (const __attribute__((address_space(1))) void*)src,
          (__attribute__((address_space(3))) void*)(Bs + qq * 16), 16, 0, 0);
    }
    asm volatile("s_waitcnt vmcnt(0)" ::: "memory");
    __syncthreads();

#pragma unroll
    for (int ks = 0; ks < 2; ++ks) {
      bf16x8 af[4], bfr[4];
#pragma unroll
      for (int m = 0; m < 4; ++m) {
        const int row = wr * 64 + m * 16 + (lane & 15);
        const int kb = (ks * 64 + ((lane >> 4) * 16)) ^ ((row & 7) << 4);
        af[m] = *(const bf16x8*)(As + row * 128 + kb);
      }
#pragma unroll
      for (int n = 0; n < 4; ++n) {
        const int row = wc * 64 + n * 16 + (lane & 15);
        const int kb = (ks * 64 + ((lane >> 4) * 16)) ^ ((row & 7) << 4);
        bfr[n] = *(const bf16x8*)(Bs + row * 128 + kb);
      }
#pragma unroll
      for (int m = 0; m < 4; ++m)
#pragma unroll
        for (int n = 0; n < 4; ++n)
          acc[m][n] = __builtin_amdgcn_mfma_f32_16x16x32_bf16(
              af[m], bfr[n], acc[m][n], 0, 0, 0);
    }
  }

  // epilogue: C/D layout col = lane&15, row = (lane>>4)*4 + j  [m89/m91]
  const int cc = lane & 15;
  const int cr0 = (lane >> 4) * 4;
#pragma unroll
  for (int m = 0; m < 4; ++m) {
#pragma unroll
    for (int n = 0; n < 4; ++n) {
#pragma unroll
      for (int j = 0; j < 4; ++j) {
        const int grow = m0 + wr * 64 + m * 16 + cr0 + j;
        const int lcol = wc * 64 + n * 16 + cc;
        const float v = acc[m][n][j];
        if constexpr (EPI == EPI_BF16) {
          ((unsigned short*)Cp)[(size_t)grow * ldc + bn0 + lcol] = f2bf(v);
        } else if constexpr (EPI == EPI_KE) {
          int ar = grow;
          if (tokA) { ar = tokA[grow]; if (ar < 0) ar = 0; }
          const float ksv = bf2f(aux[(size_t)ar * ldaux + bn0 + lcol]);
          float rr = ksv + 2.0f * v;  // LORA_SCALING = 2
          rr = rr > 0.f ? rr : 0.f;
          ((unsigned short*)Cp + (size_t)k * strideCslot)
              [(size_t)grow * ldc + bn0 + lcol] = f2bf(rr * rr);
        } else if constexpr (EPI == EPI_GV) {
          if (vatBlk) {
            if (lcol < 64)
              (vatp + (size_t)k * strideVat)[(size_t)grow * 64 + lcol] = f2bf(v);
          } else {
            const int t = crowmap[k * PRr + grow];
            if (t >= 0) {
              const float g = gate[k * MCr + t] * scale;
              ((float*)Cp + (size_t)k * strideCslot)[(size_t)t * ldc + bn0 + lcol] =
                  g * v;
            }
          }
        } else if constexpr (EPI == EPI_VB0) {
          const int t = crowmap[grow];
          if (t >= 0) {
            const float g = gate[t] * scale;
            float* o = (float*)Cp + (size_t)t * ldc + bn0 + lcol;
            *o = *o + g * v;
          }
        } else {  // EPI_VB1
          const int t = crowmap[grow];
          if (t >= 0) {
            const float g = gate[t] * scale;
            float* o = (float*)Cp + (size_t)t * ldc + bn0 + lcol;
            *o = *o + out2[(size_t)t * ldc + bn0 + lcol] + g * v;
          }
        }
      }
    }
  }
}

// ---------------------------------------------------------------------------
extern "C" void kernel_launch(void* const* d_in, const int* in_sizes, int n_in,
                              void* d_out, int out_size, void* d_ws,
                              size_t ws_size, hipStream_t stream) {
  (void)in_sizes; (void)n_in; (void)out_size;
  const float* x      = (const float*)d_in[0];
  const float* x_prev = (const float*)d_in[1];
  const float* x_k    = (const float*)d_in[2];
  const float* Router = (const float*)d_in[3];
  const float* K_ref  = (const float*)d_in[4];
  const float* V_ref  = (const float*)d_in[5];
  const float* Ka     = (const float*)d_in[6];
  const float* Kb     = (const float*)d_in[7];
  const float* Va     = (const float*)d_in[8];
  const float* Vb     = (const float*)d_in[9];

  constexpr int Bb = 4, T = 2048, C = 2048, H = 8192, R = 64, E = 4;
  constexpr int M = Bb * T;       // 8192 tokens
  constexpr int NKL = H + E * R;  // 8448: [ksh | lora] cols = KtKa rows

  const size_t PAD = 255;
  auto rnd = [&](size_t b) { return (b + PAD) & ~PAD; };
  const size_t persist = rnd((size_t)NKL * C * 2)     // KtKa
                       + rnd((size_t)C * H * 2)       // Vt
                       + rnd((size_t)E * H * R * 2)   // KbB
                       + rnd((size_t)E * R * H * 2)   // VaB
                       + rnd((size_t)E * C * R * 2)   // VbB
                       + rnd(256);                    // zero page

  // largest MC (pow2 mult of 256): single k_e (aliases h_c), ksl [MC][NKL]
  // (aliases out2 f32), sequential slots.
  int MC = 0;
  for (int cand = M; cand >= 1024; cand >>= 1) {
    const int mb = cand / 128 + 4;
    const long long pr = (long long)mb * 128;
    size_t keSpan = rnd((size_t)pr * H * 2);            // k_e  >= h_c
    if (keSpan < rnd((size_t)cand * C * 2)) keSpan = rnd((size_t)cand * C * 2);
    size_t kslSpan = rnd((size_t)cand * NKL * 2);       // ksl >= out2 f32
    if (kslSpan < rnd((size_t)cand * C * 4)) kslSpan = rnd((size_t)cand * C * 4);
    const size_t need = persist + keSpan + kslSpan
                      + rnd((size_t)2 * pr * 64 * 2)    // vat[2]
                      + rnd((size_t)(32 + 2 * mb + 2 * pr) * 4)
                      + rnd((size_t)2 * cand * 4)       // etok
                      + rnd((size_t)2 * cand * 4);      // gtok
    if (need <= ws_size) { MC = cand; break; }
  }
  if (MC == 0) return;
  const int MB = MC / 128 + 4;
  const int PR = MB * 128;

  char* ws = (char*)d_ws;
  size_t off = 0;
  auto alloc = [&](size_t bytes) -> char* {
    char* p = ws + off; off += rnd(bytes); return p;
  };
  unsigned short* KtKa = (unsigned short*)alloc((size_t)NKL * C * 2);
  unsigned short* Vt   = (unsigned short*)alloc((size_t)C * H * 2);
  unsigned short* KbB  = (unsigned short*)alloc((size_t)E * H * R * 2);
  unsigned short* VaB  = (unsigned short*)alloc((size_t)E * R * H * 2);
  unsigned short* VbB  = (unsigned short*)alloc((size_t)E * C * R * 2);
  unsigned short* zp   = (unsigned short*)alloc(256);
  size_t keBytes = rnd((size_t)PR * H * 2);
  if (keBytes < rnd((size_t)MC * C * 2)) keBytes = rnd((size_t)MC * C * 2);
  unsigned short* k_e  = (unsigned short*)alloc(keBytes);
  size_t kslBytes = rnd((size_t)MC * NKL * 2);
  if (kslBytes < rnd((size_t)MC * C * 4)) kslBytes = rnd((size_t)MC * C * 4);
  unsigned short* ksl  = (unsigned short*)alloc(kslBytes);
  unsigned short* vat  = (unsigned short*)alloc((size_t)2 * PR * 64 * 2);
  int*            tbl  = (int*)alloc((size_t)(32 + 2 * MB + 2 * PR) * 4);
  int*            etok = (int*)alloc((size_t)2 * MC * 4);
  float*          gtok = (float*)alloc((size_t)2 * MC * 4);
  unsigned short* h_c  = k_e;          // alias: h dead after kshlora GEMM
  float*          out2 = (float*)ksl;  // alias: ksl dead after KE slot1

  float* out    = (float*)d_out;
  float* x_last = out + (size_t)M * C;

  // ---- one-time: weights -> bf16 (KtKa = [K_ref^T ; KaAll]) ----
  transpose_cast<<<dim3(H / 32, C / 32), dim3(32, 8), 0, stream>>>(K_ref, KtKa, C, H);
  cast_bf16<<<(E * R * C / 4 + 255) / 256, 256, 0, stream>>>(
      Ka, KtKa + (size_t)H * C, E * R * C / 4);
  transpose_cast<<<dim3(C / 32, H / 32), dim3(32, 8), 0, stream>>>(V_ref, Vt, H, C);
  cast_bf16<<<(E * H * R / 4 + 255) / 256, 256, 0, stream>>>(Kb, KbB, E * H * R / 4);
  cast_bf16<<<(E * R * H / 4 + 255) / 256, 256, 0, stream>>>(Va, VaB, E * R * H / 4);
  cast_bf16<<<(E * C * R / 4 + 255) / 256, 256, 0, stream>>>(Vb, VbB, E * C * R / 4);
  zero_page<<<1, 64, 0, stream>>>((unsigned int*)zp);
  xlast_kernel<<<Bb * C / 4 / 256, 256, 0, stream>>>(x, x_last);

  // ---- per-chunk pipeline (sequential slots, single k_e) ----
  for (int c0 = 0; c0 < M; c0 += MC) {
    float* outc = out + (size_t)c0 * C;
    prep_kernel<<<MC * C / 4 / 256, 256, 0, stream>>>(x, x_prev, x_k, h_c, c0);
    zero_hist<<<1, 64, 0, stream>>>(tbl);
    router_kernel<<<MC / 4, 256, 0, stream>>>(x, x_prev, x_k, Router, tbl,
                                              etok, gtok, MC, c0);
    seg_build<<<1, 128, 0, stream>>>(tbl, MB);
    scatter_build<<<(MC + 255) / 256, 256, 0, stream>>>(tbl, etok, MC, MB);

    const int* bt  = tbl + 32;
    const int* tok = tbl + 32 + 2 * MB;

    // [ksh | lora] = h @ [K_ref^T ; KaAll]  [MC x 8448], K=C — 128^2 GEMM
    // (reads h_c before it is overwritten by k_e)
    gemm_bt<EPI_BF16><<<(NKL / 128) * (MC / 128), 256, 0, stream>>>(
        h_c, C, 0, 0, KtKa, C, 0, nullptr, nullptr, ksl, NKL, 0,
        nullptr, 0, nullptr, 0, nullptr, nullptr, 0.f,
        nullptr, nullptr, nullptr, C, NKL / 128, 0, PR, MC);

    for (int k = 0; k < 2; ++k) {
      const int* btk  = bt + k * MB;
      const int* tokk = tok + k * PR;
      const float* gk = gtok + (size_t)k * MC;

      // k_e = relu(ksh[tok] + 2*lora[tok,e] @ Kb[e]^T)^2  [PR x H], K=R
      // A = lora part of ksl (cols H + e*64), aux = ksh part (cols 0..H)
      gemm_bt<EPI_KE><<<(H / 128) * MB, 256, 0, stream>>>(
          ksl + H, NKL, 64, 0, KbB, R, (long long)H * R, nullptr, nullptr,
          k_e, H, 0, nullptr, 0, ksl, NKL, nullptr, nullptr, 0.f,
          btk, tokk, nullptr, R, H / 128, 0, PR, MC);

      // pure-write GV: slot0 -> out f32, slot1 -> out2 f32 (ksl alias; ksl
      // dead after the k=1 KE above); vat tile via VaB/zp
      gemm_bt<EPI_GV><<<(C / 128 + 1) * MB, 256, 0, stream>>>(
          k_e, H, 0, 0, Vt, H, 0, VaB, zp,
          (k == 0) ? (void*)outc : (void*)out2, C, 0,
          vat + (size_t)k * PR * 64, 0, nullptr, 0, gk, nullptr, 1.0f,
          btk, nullptr, tokk, H, C / 128 + 1, 0, PR, MC);

      // out += [k==1: out2] + 2*g*(vat_k @ Vb[e]^T)   [PR x C], K=R
      if (k == 0) {
        gemm_bt<EPI_VB0><<<(C / 128) * MB, 256, 0, stream>>>(
            vat, 64, 0, 0, VbB, R, (long long)C * R, nullptr, nullptr,
            outc, C, 0, nullptr, 0, nullptr, 0, gk, nullptr, 2.0f,
            btk, nullptr, tokk, R, C / 128, 0, PR, MC);
      } else {
        gemm_bt<EPI_VB1><<<(C / 128) * MB, 256, 0, stream>>>(
            vat + (size_t)PR * 64, 64, 0, 0, VbB, R, (long long)C * R,
            nullptr, nullptr, outc, C, 0, nullptr, 0, nullptr, 0,
            gk, out2, 2.0f,
            btk, nullptr, tokk, R, C / 128, 0, PR, MC);
      }
    }
  }
}